// Round 10
// baseline (299.822 us; speedup 1.0000x reference)
//
#include <hip/hip_runtime.h>
#include <hip/hip_bf16.h>

#define HSEQ 16777216   // 512*32*1024
#define NH 1024

typedef __attribute__((ext_vector_type(8))) short bf16x8;
typedef __attribute__((ext_vector_type(4))) float f32x4;

__device__ __forceinline__ unsigned short f2bf(float f) {
  unsigned u = __builtin_bit_cast(unsigned, f);
  u += 0x7fffu + ((u >> 16) & 1u);
  return (unsigned short)(u >> 16);
}

__device__ __forceinline__ float fsig(float z) {   // 1/(1+e^-z)
  float e = __builtin_amdgcn_exp2f(-1.442695041f * z);
  return __builtin_amdgcn_rcpf(1.f + e);
}
__device__ __forceinline__ float ftanh(float z) {  // 1 - 2/(e^{2z}+1)
  float e = __builtin_amdgcn_exp2f(2.885390082f * z);
  return 1.f - 2.f * __builtin_amdgcn_rcpf(1.f + e);
}

// Fused fp32->bf16 conversion: x (blocks 0-2047) + 4 gate weights (blocks 2048-3071).
__global__ __launch_bounds__(256) void cvt_all(
    const float* __restrict__ x,
    const float* __restrict__ wi, const float* __restrict__ wf,
    const float* __restrict__ wo, const float* __restrict__ wg,
    unsigned short* __restrict__ xb, unsigned short* __restrict__ wb) {
  int bid = blockIdx.x;
  const float* src; unsigned short* dst; int base, iters;
  if (bid < 2048) {
    src = x; dst = xb; base = bid * 8192; iters = 8;
  } else {
    int g = bid - 2048; int ws = g >> 8; int blk = g & 255;
    src = (ws == 0) ? wi : (ws == 1) ? wf : (ws == 2) ? wo : wg;
    dst = wb + ws * 1048576; base = blk * 4096; iters = 4;
  }
  int t = threadIdx.x;
  for (int i = 0; i < iters; ++i) {
    int idx = base + i * 1024 + t * 4;
    float4 v = *reinterpret_cast<const float4*>(src + idx);
    ushort4 o;
    o.x = f2bf(v.x); o.y = f2bf(v.y); o.z = f2bf(v.z); o.w = f2bf(v.w);
    *reinterpret_cast<ushort4*>(dst + idx) = o;
  }
}

// hz[g][b][h] = h0[b,:]·w_h[g][h,:] + b_i[g][h] + b_h[g][h]
__global__ __launch_bounds__(256) void hz_kernel(
    const float* __restrict__ h0,
    const float* __restrict__ wh_i, const float* __restrict__ wh_f,
    const float* __restrict__ wh_o, const float* __restrict__ wh_g,
    const float* __restrict__ bi_i, const float* __restrict__ bh_i,
    const float* __restrict__ bi_f, const float* __restrict__ bh_f,
    const float* __restrict__ bi_o, const float* __restrict__ bh_o,
    const float* __restrict__ bi_g, const float* __restrict__ bh_g,
    float* __restrict__ hz) {
  __shared__ float ws[8 * 1024];
  int g = blockIdx.x >> 7;
  int hb = blockIdx.x & 127;
  const float* wh = (g == 0) ? wh_i : (g == 1) ? wh_f : (g == 2) ? wh_o : wh_g;
  const float* bi = (g == 0) ? bi_i : (g == 1) ? bi_f : (g == 2) ? bi_o : bi_g;
  const float* bh = (g == 0) ? bh_i : (g == 1) ? bh_f : (g == 2) ? bh_o : bh_g;
  int tid = threadIdx.x;
  const float4* wsrc = reinterpret_cast<const float4*>(wh + hb * 8 * 1024);
  float4* wdst = reinterpret_cast<float4*>(ws);
  for (int i = tid; i < 2048; i += 256) wdst[i] = wsrc[i];
  __syncthreads();
  int b = tid & 31;
  int hh = tid >> 5;
  const float4* hv = reinterpret_cast<const float4*>(h0 + b * NH);
  const float4* wv = reinterpret_cast<const float4*>(ws + hh * NH);
  float acc = 0.f;
  for (int k = 0; k < 256; ++k) {
    float4 a = hv[k], w4 = wv[k];
    acc += a.x * w4.x + a.y * w4.y + a.z * w4.z + a.w * w4.w;
  }
  int h = hb * 8 + hh;
  hz[g * (32 * NH) + b * NH + h] = acc + bi[h] + bh[h];
}

__device__ __forceinline__ void load_lds16(const void* gsrc, void* lds) {
  __builtin_amdgcn_global_load_lds(
      (const __attribute__((address_space(1))) unsigned int*)gsrc,
      (__attribute__((address_space(3))) unsigned int*)lds, 16, 0, 0);
}

// 128 x (4g x 32h) tile, BK=64, single-buffered LDS (32KB), 4 waves in a
// 2x2 grid (minimum-LDS-traffic split: 16 ds_read_b128/wave/kt vs 20 for
// the 1x4 split; per-CU-kt LDS traffic 96KB vs 112KB). TLP-first:
// __launch_bounds__(256,4) -> ~4 blocks/CU hide stage latency (R9-verified).
// T2 XOR swizzle keeps reads conflict-free; XCD swizzle gives each XCD a
// disjoint 16-mt A-range.
__global__ __launch_bounds__(256, 4) void lstm_gemm(
    const unsigned short* __restrict__ xb,   // [16384][1024] bf16
    const unsigned short* __restrict__ wb,   // [4][1024][1024] bf16 (i,f,o,g)
    const float* __restrict__ hz,            // [4][32][1024] f32
    const float* __restrict__ c0,            // [32][1024] f32
    float* __restrict__ out) {
  __shared__ unsigned short As[128 * 64];    // 16 KB
  __shared__ unsigned short Bs[128 * 64];    // 16 KB

  const int orig = blockIdx.x;               // 4096 blocks, 4096%8==0
  const int bid = (orig & 7) * 512 + (orig >> 3);   // XCD swizzle
  const int mt = bid >> 5;                   // 0..127 (disjoint 16-mt range/XCD)
  const int ht = bid & 31;                   // 0..31
  const int mBase = mt * 128;
  const int hBase = ht * 32;

  const int tid = threadIdx.x;
  const int lane = tid & 63;
  const int w = tid >> 6;                    // 0..3
  const int wr = w >> 1;                     // 0..1 (m half)
  const int wc = w & 1;                      // 0..1 (h 16-group)
  const int laneLow = lane & 15;
  const int lane4 = lane >> 4;               // 0..3
  const int lx = lane & 7;

  // staging geometry: unit = 8 rows x 64 cols (1KB); lane covers row sR, 16B
  const int sR = lane >> 3;                  // 0..7
  const int sL = ((lane & 7) ^ sR) * 8;      // inverse-swizzled logical col

  f32x4 acc[4][4];                           // [mi][gate]
#pragma unroll
  for (int i = 0; i < 4; ++i)
#pragma unroll
    for (int j = 0; j < 4; ++j) acc[i][j] = (f32x4){0.f, 0.f, 0.f, 0.f};

  for (int kt = 0; kt < 16; ++kt) {
    const int k0 = kt * 64;
    // stage A: 16 units, wave w does units j*4+w
#pragma unroll
    for (int j = 0; j < 4; ++j) {
      int c = j * 4 + w;
      int row = c * 8 + sR;
      load_lds16(xb + (size_t)(mBase + row) * 1024 + k0 + sL, As + c * 512);
    }
    // stage B (eff-N rows: n = gate*32 + hh)
#pragma unroll
    for (int j = 0; j < 4; ++j) {
      int c = j * 4 + w;
      int n = c * 8 + sR;
      int gate = n >> 5, hh = n & 31;
      load_lds16(wb + (size_t)gate * 1048576 + (size_t)(hBase + hh) * 1024 + k0 + sL,
                 Bs + c * 512);
    }
    asm volatile("s_waitcnt vmcnt(0)" ::: "memory");
    __builtin_amdgcn_s_barrier();

    // A fragments: rows wr*64 + mi*16 + laneLow, mi=0..3
    bf16x8 af[4][2];
#pragma unroll
    for (int mi = 0; mi < 4; ++mi)
#pragma unroll
      for (int kk = 0; kk < 2; ++kk) {
        int row = wr * 64 + mi * 16 + laneLow;
        int slot = (kk * 4 + lane4) ^ lx;
        af[mi][kk] = *reinterpret_cast<const bf16x8*>(&As[row * 64 + slot * 8]);
      }
    // per-gate B fragments (rows g*32 + wc*16 + laneLow) + MFMAs
#pragma unroll
    for (int g = 0; g < 4; ++g) {
      int n = g * 32 + wc * 16 + laneLow;
      int slot0 = lane4 ^ lx;
      int slot1 = (4 + lane4) ^ lx;
      bf16x8 b0 = *reinterpret_cast<const bf16x8*>(&Bs[n * 64 + slot0 * 8]);
      bf16x8 b1 = *reinterpret_cast<const bf16x8*>(&Bs[n * 64 + slot1 * 8]);
#pragma unroll
      for (int mi = 0; mi < 4; ++mi) {
        acc[mi][g] = __builtin_amdgcn_mfma_f32_16x16x32_bf16(af[mi][0], b0, acc[mi][g], 0, 0, 0);
        acc[mi][g] = __builtin_amdgcn_mfma_f32_16x16x32_bf16(af[mi][1], b1, acc[mi][g], 0, 0, 0);
      }
    }
    __builtin_amdgcn_s_barrier();
  }

  // epilogue: thread holds all 4 gates for h = hBase + wc*16 + laneLow,
  // rows m = mBase + wr*64 + mi*16 + lane4*4 + r
  const int b = mBase >> 9;  // uniform per block (128 | 512)
  const int h = hBase + wc * 16 + laneLow;
  const float hz_i = hz[0 * 32768 + b * NH + h];
  const float hz_f = hz[1 * 32768 + b * NH + h];
  const float hz_o = hz[2 * 32768 + b * NH + h];
  const float hz_g = hz[3 * 32768 + b * NH + h];
  const float c0v = c0[b * NH + h];
#pragma unroll
  for (int mi = 0; mi < 4; ++mi) {
#pragma unroll
    for (int r = 0; r < 4; ++r) {
      int m = mBase + wr * 64 + mi * 16 + lane4 * 4 + r;
      int t = m & 511;
      float zi = acc[mi][0][r] + hz_i;
      float zf = acc[mi][1][r] + hz_f;
      float zo = acc[mi][2][r] + hz_o;
      float zg = acc[mi][3][r] + hz_g;
      float iv = fsig(zi);
      float fv = fsig(zf);
      float ov = fsig(zo);
      float gv = ftanh(zg);
      float cv = fv * c0v + iv * gv;
      float hval = ov * ftanh(cv);
      out[((size_t)t * 32 + b) * 1024 + h] = hval;
      if (t == 511) {
        out[HSEQ + b * NH + h] = hval;
        out[HSEQ + 32768 + b * NH + h] = cv;
      }
    }
  }
}

extern "C" void kernel_launch(void* const* d_in, const int* in_sizes, int n_in,
                              void* d_out, int out_size, void* d_ws, size_t ws_size,
                              hipStream_t stream) {
  const float* x    = (const float*)d_in[0];
  const float* h0   = (const float*)d_in[1];
  const float* c0   = (const float*)d_in[2];
  const float* w_ii = (const float*)d_in[3];
  const float* b_ii = (const float*)d_in[4];
  const float* w_hi = (const float*)d_in[5];
  const float* b_hi = (const float*)d_in[6];
  const float* w_if = (const float*)d_in[7];
  const float* b_if = (const float*)d_in[8];
  const float* w_hf = (const float*)d_in[9];
  const float* b_hf = (const float*)d_in[10];
  const float* w_io = (const float*)d_in[11];
  const float* b_io = (const float*)d_in[12];
  const float* w_ho = (const float*)d_in[13];
  const float* b_ho = (const float*)d_in[14];
  const float* w_ig = (const float*)d_in[15];
  const float* b_ig = (const float*)d_in[16];
  const float* w_hg = (const float*)d_in[17];
  const float* b_hg = (const float*)d_in[18];

  unsigned short* xb = (unsigned short*)d_ws;          // 16777216 bf16
  unsigned short* wb = xb + 16777216;                  // 4*1048576 bf16
  float* hz = (float*)(wb + 4 * 1048576);              // 4*32*1024 f32
  float* out = (float*)d_out;

  hipLaunchKernelGGL(cvt_all, dim3(3072), dim3(256), 0, stream,
                     x, w_ii, w_if, w_io, w_ig, xb, wb);
  hipLaunchKernelGGL(hz_kernel, dim3(512), dim3(256), 0, stream, h0,
                     w_hi, w_hf, w_ho, w_hg,
                     b_ii, b_hi, b_if, b_hf, b_io, b_ho, b_ig, b_hg, hz);
  hipLaunchKernelGGL(lstm_gemm, dim3(4096), dim3(256), 0, stream, xb, wb, hz, c0, out);
}

// Round 11
// 242.528 us; speedup vs baseline: 1.2362x; 1.2362x over previous
//
#include <hip/hip_runtime.h>
#include <hip/hip_bf16.h>

#define HSEQ 16777216   // 512*32*1024
#define NH 1024

typedef __attribute__((ext_vector_type(8))) short bf16x8;
typedef __attribute__((ext_vector_type(4))) float f32x4;

__device__ __forceinline__ unsigned short f2bf(float f) {
  unsigned u = __builtin_bit_cast(unsigned, f);
  u += 0x7fffu + ((u >> 16) & 1u);
  return (unsigned short)(u >> 16);
}

__device__ __forceinline__ float fsig(float z) {   // 1/(1+e^-z)
  float e = __builtin_amdgcn_exp2f(-1.442695041f * z);
  return __builtin_amdgcn_rcpf(1.f + e);
}
__device__ __forceinline__ float ftanh(float z) {  // 1 - 2/(e^{2z}+1)
  float e = __builtin_amdgcn_exp2f(2.885390082f * z);
  return 1.f - 2.f * __builtin_amdgcn_rcpf(1.f + e);
}

// Fused fp32->bf16 conversion: x (blocks 0-2047) + 4 gate weights (blocks 2048-3071).
__global__ __launch_bounds__(256) void cvt_all(
    const float* __restrict__ x,
    const float* __restrict__ wi, const float* __restrict__ wf,
    const float* __restrict__ wo, const float* __restrict__ wg,
    unsigned short* __restrict__ xb, unsigned short* __restrict__ wb) {
  int bid = blockIdx.x;
  const float* src; unsigned short* dst; int base, iters;
  if (bid < 2048) {
    src = x; dst = xb; base = bid * 8192; iters = 8;
  } else {
    int g = bid - 2048; int ws = g >> 8; int blk = g & 255;
    src = (ws == 0) ? wi : (ws == 1) ? wf : (ws == 2) ? wo : wg;
    dst = wb + ws * 1048576; base = blk * 4096; iters = 4;
  }
  int t = threadIdx.x;
  for (int i = 0; i < iters; ++i) {
    int idx = base + i * 1024 + t * 4;
    float4 v = *reinterpret_cast<const float4*>(src + idx);
    ushort4 o;
    o.x = f2bf(v.x); o.y = f2bf(v.y); o.z = f2bf(v.z); o.w = f2bf(v.w);
    *reinterpret_cast<ushort4*>(dst + idx) = o;
  }
}

// hz[g][b][h] = h0[b,:]·w_h[g][h,:] + b_i[g][h] + b_h[g][h]
__global__ __launch_bounds__(256) void hz_kernel(
    const float* __restrict__ h0,
    const float* __restrict__ wh_i, const float* __restrict__ wh_f,
    const float* __restrict__ wh_o, const float* __restrict__ wh_g,
    const float* __restrict__ bi_i, const float* __restrict__ bh_i,
    const float* __restrict__ bi_f, const float* __restrict__ bh_f,
    const float* __restrict__ bi_o, const float* __restrict__ bh_o,
    const float* __restrict__ bi_g, const float* __restrict__ bh_g,
    float* __restrict__ hz) {
  __shared__ float ws[8 * 1024];
  int g = blockIdx.x >> 7;
  int hb = blockIdx.x & 127;
  const float* wh = (g == 0) ? wh_i : (g == 1) ? wh_f : (g == 2) ? wh_o : wh_g;
  const float* bi = (g == 0) ? bi_i : (g == 1) ? bi_f : (g == 2) ? bi_o : bi_g;
  const float* bh = (g == 0) ? bh_i : (g == 1) ? bh_f : (g == 2) ? bh_o : bh_g;
  int tid = threadIdx.x;
  const float4* wsrc = reinterpret_cast<const float4*>(wh + hb * 8 * 1024);
  float4* wdst = reinterpret_cast<float4*>(ws);
  for (int i = tid; i < 2048; i += 256) wdst[i] = wsrc[i];
  __syncthreads();
  int b = tid & 31;
  int hh = tid >> 5;
  const float4* hv = reinterpret_cast<const float4*>(h0 + b * NH);
  const float4* wv = reinterpret_cast<const float4*>(ws + hh * NH);
  float acc = 0.f;
  for (int k = 0; k < 256; ++k) {
    float4 a = hv[k], w4 = wv[k];
    acc += a.x * w4.x + a.y * w4.y + a.z * w4.z + a.w * w4.w;
  }
  int h = hb * 8 + hh;
  hz[g * (32 * NH) + b * NH + h] = acc + bi[h] + bh[h];
}

__device__ __forceinline__ void load_lds16(const void* gsrc, void* lds) {
  __builtin_amdgcn_global_load_lds(
      (const __attribute__((address_space(1))) unsigned int*)gsrc,
      (__attribute__((address_space(3))) unsigned int*)lds, 16, 0, 0);
}
// NT/streaming variant (aux=2 = SLC/NT on gfx9-family): cache hint only.
__device__ __forceinline__ void load_lds16_nt(const void* gsrc, void* lds) {
  __builtin_amdgcn_global_load_lds(
      (const __attribute__((address_space(1))) unsigned int*)gsrc,
      (__attribute__((address_space(3))) unsigned int*)lds, 16, 0, 2);
}

// R9 gemm (verified 144us) with ONE change: cache-shaped partition.
// XCD x owns mt in [32*(x>>1), +32) x ht in [16*(x&1), +16):
//   - B slice/XCD = 4MB = L2, reused by 32 mt-blocks -> resident
//   - A streamed once/XCD (8MB); ht-inner order makes the 16 consumers of an
//     A panel co-resident (cohort = 8 mt x 16 ht)
//   - A staged with NT hint so the stream doesn't evict resident B.
__global__ __launch_bounds__(256, 4) void lstm_gemm(
    const unsigned short* __restrict__ xb,   // [16384][1024] bf16
    const unsigned short* __restrict__ wb,   // [4][1024][1024] bf16 (i,f,o,g)
    const float* __restrict__ hz,            // [4][32][1024] f32
    const float* __restrict__ c0,            // [32][1024] f32
    float* __restrict__ out) {
  __shared__ unsigned short As[128 * 64];    // 16 KB
  __shared__ unsigned short Bs[128 * 64];    // 16 KB

  const int orig = blockIdx.x;               // 4096 blocks
  const int xcd = orig & 7;
  const int local = orig >> 3;               // 0..511, ht-inner
  const int mt = (xcd >> 1) * 32 + (local >> 4);   // 0..127
  const int ht = (xcd & 1) * 16 + (local & 15);    // 0..31
  const int mBase = mt * 128;
  const int hBase = ht * 32;

  const int tid = threadIdx.x;
  const int lane = tid & 63;
  const int w = tid >> 6;                    // 0..3
  const int laneLow = lane & 15;
  const int lane4 = lane >> 4;               // 0..3

  // staging geometry: unit = 8 rows x 64 cols (1KB); lane covers row sR, 16B
  const int sR = lane >> 3;                  // 0..7
  const int sL = ((lane & 7) ^ sR) * 8;      // inverse-swizzled logical col

  f32x4 acc[2][8];
#pragma unroll
  for (int i = 0; i < 2; ++i)
#pragma unroll
    for (int j = 0; j < 8; ++j) acc[i][j] = (f32x4){0.f, 0.f, 0.f, 0.f};

  for (int kt = 0; kt < 16; ++kt) {
    const int k0 = kt * 64;
    // stage A (NT): 16 units, wave w does units j*4+w
#pragma unroll
    for (int j = 0; j < 4; ++j) {
      int c = j * 4 + w;
      int row = c * 8 + sR;
      load_lds16_nt(xb + (size_t)(mBase + row) * 1024 + k0 + sL, As + c * 512);
    }
    // stage B (eff-N rows: n = gate*32 + hh)
#pragma unroll
    for (int j = 0; j < 4; ++j) {
      int c = j * 4 + w;
      int n = c * 8 + sR;
      int gate = n >> 5, hh = n & 31;
      load_lds16(wb + (size_t)gate * 1048576 + (size_t)(hBase + hh) * 1024 + k0 + sL,
                 Bs + c * 512);
    }
    asm volatile("s_waitcnt vmcnt(0)" ::: "memory");
    __builtin_amdgcn_s_barrier();

    bf16x8 af[2][2];
#pragma unroll
    for (int mi = 0; mi < 2; ++mi)
#pragma unroll
      for (int kk = 0; kk < 2; ++kk) {
        int row = w * 32 + mi * 16 + laneLow;
        int slot = (kk * 4 + lane4) ^ (laneLow & 7);
        af[mi][kk] = *reinterpret_cast<const bf16x8*>(&As[row * 64 + slot * 8]);
      }
#pragma unroll
    for (int nf = 0; nf < 8; ++nf) {
      bf16x8 bfb0, bfb1;
      {
        int n = nf * 16 + laneLow;
        int slot0 = (0 * 4 + lane4) ^ (laneLow & 7);
        int slot1 = (1 * 4 + lane4) ^ (laneLow & 7);
        bfb0 = *reinterpret_cast<const bf16x8*>(&Bs[n * 64 + slot0 * 8]);
        bfb1 = *reinterpret_cast<const bf16x8*>(&Bs[n * 64 + slot1 * 8]);
      }
      acc[0][nf] = __builtin_amdgcn_mfma_f32_16x16x32_bf16(af[0][0], bfb0, acc[0][nf], 0, 0, 0);
      acc[1][nf] = __builtin_amdgcn_mfma_f32_16x16x32_bf16(af[1][0], bfb0, acc[1][nf], 0, 0, 0);
      acc[0][nf] = __builtin_amdgcn_mfma_f32_16x16x32_bf16(af[0][1], bfb1, acc[0][nf], 0, 0, 0);
      acc[1][nf] = __builtin_amdgcn_mfma_f32_16x16x32_bf16(af[1][1], bfb1, acc[1][nf], 0, 0, 0);
    }
    __builtin_amdgcn_s_barrier();
  }

  // epilogue: combine gates (R2-verified layout), cheap activations, f32 writes
  const int b = mBase >> 9;  // uniform per block (128 | 512)
#pragma unroll
  for (int mi = 0; mi < 2; ++mi) {
#pragma unroll
    for (int n16 = 0; n16 < 2; ++n16) {
      int h = hBase + n16 * 16 + laneLow;
      float hz_i = hz[0 * 32768 + b * NH + h];
      float hz_f = hz[1 * 32768 + b * NH + h];
      float hz_o = hz[2 * 32768 + b * NH + h];
      float hz_g = hz[3 * 32768 + b * NH + h];
      float c0v = c0[b * NH + h];
#pragma unroll
      for (int r = 0; r < 4; ++r) {
        int row = w * 32 + mi * 16 + lane4 * 4 + r;
        int m = mBase + row;
        int t = m & 511;
        float zi = acc[mi][0 + n16][r] + hz_i;
        float zf = acc[mi][2 + n16][r] + hz_f;
        float zo = acc[mi][4 + n16][r] + hz_o;
        float zg = acc[mi][6 + n16][r] + hz_g;
        float iv = fsig(zi);
        float fv = fsig(zf);
        float ov = fsig(zo);
        float gv = ftanh(zg);
        float cv = fv * c0v + iv * gv;
        float hval = ov * ftanh(cv);
        out[((size_t)t * 32 + b) * 1024 + h] = hval;
        if (t == 511) {
          out[HSEQ + b * NH + h] = hval;
          out[HSEQ + 32768 + b * NH + h] = cv;
        }
      }
    }
  }
}

extern "C" void kernel_launch(void* const* d_in, const int* in_sizes, int n_in,
                              void* d_out, int out_size, void* d_ws, size_t ws_size,
                              hipStream_t stream) {
  const float* x    = (const float*)d_in[0];
  const float* h0   = (const float*)d_in[1];
  const float* c0   = (const float*)d_in[2];
  const float* w_ii = (const float*)d_in[3];
  const float* b_ii = (const float*)d_in[4];
  const float* w_hi = (const float*)d_in[5];
  const float* b_hi = (const float*)d_in[6];
  const float* w_if = (const float*)d_in[7];
  const float* b_if = (const float*)d_in[8];
  const float* w_hf = (const float*)d_in[9];
  const float* b_hf = (const float*)d_in[10];
  const float* w_io = (const float*)d_in[11];
  const float* b_io = (const float*)d_in[12];
  const float* w_ho = (const float*)d_in[13];
  const float* b_ho = (const float*)d_in[14];
  const float* w_ig = (const float*)d_in[15];
  const float* b_ig = (const float*)d_in[16];
  const float* w_hg = (const float*)d_in[17];
  const float* b_hg = (const float*)d_in[18];

  unsigned short* xb = (unsigned short*)d_ws;          // 16777216 bf16
  unsigned short* wb = xb + 16777216;                  // 4*1048576 bf16
  float* hz = (float*)(wb + 4 * 1048576);              // 4*32*1024 f32
  float* out = (float*)d_out;

  hipLaunchKernelGGL(cvt_all, dim3(3072), dim3(256), 0, stream,
                     x, w_ii, w_if, w_io, w_ig, xb, wb);
  hipLaunchKernelGGL(hz_kernel, dim3(512), dim3(256), 0, stream, h0,
                     w_hi, w_hf, w_ho, w_hg,
                     b_ii, b_hi, b_if, b_hf, b_io, b_ho, b_ig, b_hg, hz);
  hipLaunchKernelGGL(lstm_gemm, dim3(4096), dim3(256), 0, stream, xb, wb, hz, c0, out);
}

// Round 12
// 206.162 us; speedup vs baseline: 1.4543x; 1.1764x over previous
//
#include <hip/hip_runtime.h>
#include <hip/hip_bf16.h>

#define HSEQ 16777216   // 512*32*1024
#define NH 1024

typedef __attribute__((ext_vector_type(8))) short bf16x8;
typedef __attribute__((ext_vector_type(4))) float f32x4;

__device__ __forceinline__ unsigned short f2bf(float f) {
  unsigned u = __builtin_bit_cast(unsigned, f);
  u += 0x7fffu + ((u >> 16) & 1u);
  return (unsigned short)(u >> 16);
}

__device__ __forceinline__ float fsig(float z) {   // 1/(1+e^-z)
  float e = __builtin_amdgcn_exp2f(-1.442695041f * z);
  return __builtin_amdgcn_rcpf(1.f + e);
}
__device__ __forceinline__ float ftanh(float z) {  // 1 - 2/(e^{2z}+1)
  float e = __builtin_amdgcn_exp2f(2.885390082f * z);
  return 1.f - 2.f * __builtin_amdgcn_rcpf(1.f + e);
}

// Fused fp32->bf16 conversion: x (blocks 0-2047) + 4 gate weights (blocks 2048-3071).
__global__ __launch_bounds__(256) void cvt_all(
    const float* __restrict__ x,
    const float* __restrict__ wi, const float* __restrict__ wf,
    const float* __restrict__ wo, const float* __restrict__ wg,
    unsigned short* __restrict__ xb, unsigned short* __restrict__ wb) {
  int bid = blockIdx.x;
  const float* src; unsigned short* dst; int base, iters;
  if (bid < 2048) {
    src = x; dst = xb; base = bid * 8192; iters = 8;
  } else {
    int g = bid - 2048; int ws = g >> 8; int blk = g & 255;
    src = (ws == 0) ? wi : (ws == 1) ? wf : (ws == 2) ? wo : wg;
    dst = wb + ws * 1048576; base = blk * 4096; iters = 4;
  }
  int t = threadIdx.x;
  for (int i = 0; i < iters; ++i) {
    int idx = base + i * 1024 + t * 4;
    float4 v = *reinterpret_cast<const float4*>(src + idx);
    ushort4 o;
    o.x = f2bf(v.x); o.y = f2bf(v.y); o.z = f2bf(v.z); o.w = f2bf(v.w);
    *reinterpret_cast<ushort4*>(dst + idx) = o;
  }
}

// hz[g][b][h] = h0[b,:]·w_h[g][h,:] + b_i[g][h] + b_h[g][h]
__global__ __launch_bounds__(256) void hz_kernel(
    const float* __restrict__ h0,
    const float* __restrict__ wh_i, const float* __restrict__ wh_f,
    const float* __restrict__ wh_o, const float* __restrict__ wh_g,
    const float* __restrict__ bi_i, const float* __restrict__ bh_i,
    const float* __restrict__ bi_f, const float* __restrict__ bh_f,
    const float* __restrict__ bi_o, const float* __restrict__ bh_o,
    const float* __restrict__ bi_g, const float* __restrict__ bh_g,
    float* __restrict__ hz) {
  __shared__ float ws[8 * 1024];
  int g = blockIdx.x >> 7;
  int hb = blockIdx.x & 127;
  const float* wh = (g == 0) ? wh_i : (g == 1) ? wh_f : (g == 2) ? wh_o : wh_g;
  const float* bi = (g == 0) ? bi_i : (g == 1) ? bi_f : (g == 2) ? bi_o : bi_g;
  const float* bh = (g == 0) ? bh_i : (g == 1) ? bh_f : (g == 2) ? bh_o : bh_g;
  int tid = threadIdx.x;
  const float4* wsrc = reinterpret_cast<const float4*>(wh + hb * 8 * 1024);
  float4* wdst = reinterpret_cast<float4*>(ws);
  for (int i = tid; i < 2048; i += 256) wdst[i] = wsrc[i];
  __syncthreads();
  int b = tid & 31;
  int hh = tid >> 5;
  const float4* hv = reinterpret_cast<const float4*>(h0 + b * NH);
  const float4* wv = reinterpret_cast<const float4*>(ws + hh * NH);
  float acc = 0.f;
  for (int k = 0; k < 256; ++k) {
    float4 a = hv[k], w4 = wv[k];
    acc += a.x * w4.x + a.y * w4.y + a.z * w4.z + a.w * w4.w;
  }
  int h = hb * 8 + hh;
  hz[g * (32 * NH) + b * NH + h] = acc + bi[h] + bh[h];
}

__device__ __forceinline__ void load_lds16(const void* gsrc, void* lds) {
  __builtin_amdgcn_global_load_lds(
      (const __attribute__((address_space(1))) unsigned int*)gsrc,
      (__attribute__((address_space(3))) unsigned int*)lds, 16, 0, 0);
}

// R9 gemm with the R11 cache-shaped partition, NT hint REMOVED (one-variable
// experiment: R11's regression attributed to NT's L2-bypass latency).
// XCD x owns mt in [32*(x>>1), +32) x ht in [16*(x&1), +16); ht-inner order:
// cohort/XCD = 8 mt-panels (2MB A) x 16 ht (4MB B) -> mostly L2-resident.
__global__ __launch_bounds__(256, 4) void lstm_gemm(
    const unsigned short* __restrict__ xb,   // [16384][1024] bf16
    const unsigned short* __restrict__ wb,   // [4][1024][1024] bf16 (i,f,o,g)
    const float* __restrict__ hz,            // [4][32][1024] f32
    const float* __restrict__ c0,            // [32][1024] f32
    float* __restrict__ out) {
  __shared__ unsigned short As[128 * 64];    // 16 KB
  __shared__ unsigned short Bs[128 * 64];    // 16 KB

  const int orig = blockIdx.x;               // 4096 blocks
  const int xcd = orig & 7;
  const int local = orig >> 3;               // 0..511, ht-inner
  const int mt = (xcd >> 1) * 32 + (local >> 4);   // 0..127
  const int ht = (xcd & 1) * 16 + (local & 15);    // 0..31
  const int mBase = mt * 128;
  const int hBase = ht * 32;

  const int tid = threadIdx.x;
  const int lane = tid & 63;
  const int w = tid >> 6;                    // 0..3
  const int laneLow = lane & 15;
  const int lane4 = lane >> 4;               // 0..3

  // staging geometry: unit = 8 rows x 64 cols (1KB); lane covers row sR, 16B
  const int sR = lane >> 3;                  // 0..7
  const int sL = ((lane & 7) ^ sR) * 8;      // inverse-swizzled logical col

  f32x4 acc[2][8];
#pragma unroll
  for (int i = 0; i < 2; ++i)
#pragma unroll
    for (int j = 0; j < 8; ++j) acc[i][j] = (f32x4){0.f, 0.f, 0.f, 0.f};

  for (int kt = 0; kt < 16; ++kt) {
    const int k0 = kt * 64;
    // stage A: 16 units, wave w does units j*4+w
#pragma unroll
    for (int j = 0; j < 4; ++j) {
      int c = j * 4 + w;
      int row = c * 8 + sR;
      load_lds16(xb + (size_t)(mBase + row) * 1024 + k0 + sL, As + c * 512);
    }
    // stage B (eff-N rows: n = gate*32 + hh)
#pragma unroll
    for (int j = 0; j < 4; ++j) {
      int c = j * 4 + w;
      int n = c * 8 + sR;
      int gate = n >> 5, hh = n & 31;
      load_lds16(wb + (size_t)gate * 1048576 + (size_t)(hBase + hh) * 1024 + k0 + sL,
                 Bs + c * 512);
    }
    asm volatile("s_waitcnt vmcnt(0)" ::: "memory");
    __builtin_amdgcn_s_barrier();

    bf16x8 af[2][2];
#pragma unroll
    for (int mi = 0; mi < 2; ++mi)
#pragma unroll
      for (int kk = 0; kk < 2; ++kk) {
        int row = w * 32 + mi * 16 + laneLow;
        int slot = (kk * 4 + lane4) ^ (laneLow & 7);
        af[mi][kk] = *reinterpret_cast<const bf16x8*>(&As[row * 64 + slot * 8]);
      }
#pragma unroll
    for (int nf = 0; nf < 8; ++nf) {
      bf16x8 bfb0, bfb1;
      {
        int n = nf * 16 + laneLow;
        int slot0 = (0 * 4 + lane4) ^ (laneLow & 7);
        int slot1 = (1 * 4 + lane4) ^ (laneLow & 7);
        bfb0 = *reinterpret_cast<const bf16x8*>(&Bs[n * 64 + slot0 * 8]);
        bfb1 = *reinterpret_cast<const bf16x8*>(&Bs[n * 64 + slot1 * 8]);
      }
      acc[0][nf] = __builtin_amdgcn_mfma_f32_16x16x32_bf16(af[0][0], bfb0, acc[0][nf], 0, 0, 0);
      acc[1][nf] = __builtin_amdgcn_mfma_f32_16x16x32_bf16(af[1][0], bfb0, acc[1][nf], 0, 0, 0);
      acc[0][nf] = __builtin_amdgcn_mfma_f32_16x16x32_bf16(af[0][1], bfb1, acc[0][nf], 0, 0, 0);
      acc[1][nf] = __builtin_amdgcn_mfma_f32_16x16x32_bf16(af[1][1], bfb1, acc[1][nf], 0, 0, 0);
    }
    __builtin_amdgcn_s_barrier();
  }

  // epilogue: combine gates (R2-verified layout), cheap activations, f32 writes
  const int b = mBase >> 9;  // uniform per block (128 | 512)
#pragma unroll
  for (int mi = 0; mi < 2; ++mi) {
#pragma unroll
    for (int n16 = 0; n16 < 2; ++n16) {
      int h = hBase + n16 * 16 + laneLow;
      float hz_i = hz[0 * 32768 + b * NH + h];
      float hz_f = hz[1 * 32768 + b * NH + h];
      float hz_o = hz[2 * 32768 + b * NH + h];
      float hz_g = hz[3 * 32768 + b * NH + h];
      float c0v = c0[b * NH + h];
#pragma unroll
      for (int r = 0; r < 4; ++r) {
        int row = w * 32 + mi * 16 + lane4 * 4 + r;
        int m = mBase + row;
        int t = m & 511;
        float zi = acc[mi][0 + n16][r] + hz_i;
        float zf = acc[mi][2 + n16][r] + hz_f;
        float zo = acc[mi][4 + n16][r] + hz_o;
        float zg = acc[mi][6 + n16][r] + hz_g;
        float iv = fsig(zi);
        float fv = fsig(zf);
        float ov = fsig(zo);
        float gv = ftanh(zg);
        float cv = fv * c0v + iv * gv;
        float hval = ov * ftanh(cv);
        out[((size_t)t * 32 + b) * 1024 + h] = hval;
        if (t == 511) {
          out[HSEQ + b * NH + h] = hval;
          out[HSEQ + 32768 + b * NH + h] = cv;
        }
      }
    }
  }
}

extern "C" void kernel_launch(void* const* d_in, const int* in_sizes, int n_in,
                              void* d_out, int out_size, void* d_ws, size_t ws_size,
                              hipStream_t stream) {
  const float* x    = (const float*)d_in[0];
  const float* h0   = (const float*)d_in[1];
  const float* c0   = (const float*)d_in[2];
  const float* w_ii = (const float*)d_in[3];
  const float* b_ii = (const float*)d_in[4];
  const float* w_hi = (const float*)d_in[5];
  const float* b_hi = (const float*)d_in[6];
  const float* w_if = (const float*)d_in[7];
  const float* b_if = (const float*)d_in[8];
  const float* w_hf = (const float*)d_in[9];
  const float* b_hf = (const float*)d_in[10];
  const float* w_io = (const float*)d_in[11];
  const float* b_io = (const float*)d_in[12];
  const float* w_ho = (const float*)d_in[13];
  const float* b_ho = (const float*)d_in[14];
  const float* w_ig = (const float*)d_in[15];
  const float* b_ig = (const float*)d_in[16];
  const float* w_hg = (const float*)d_in[17];
  const float* b_hg = (const float*)d_in[18];

  unsigned short* xb = (unsigned short*)d_ws;          // 16777216 bf16
  unsigned short* wb = xb + 16777216;                  // 4*1048576 bf16
  float* hz = (float*)(wb + 4 * 1048576);              // 4*32*1024 f32
  float* out = (float*)d_out;

  hipLaunchKernelGGL(cvt_all, dim3(3072), dim3(256), 0, stream,
                     x, w_ii, w_if, w_io, w_ig, xb, wb);
  hipLaunchKernelGGL(hz_kernel, dim3(512), dim3(256), 0, stream, h0,
                     w_hi, w_hf, w_ho, w_hg,
                     b_ii, b_hi, b_if, b_hf, b_io, b_ho, b_ig, b_hg, hz);
  hipLaunchKernelGGL(lstm_gemm, dim3(4096), dim3(256), 0, stream, xb, wb, hz, c0, out);
}